// Round 1
// baseline (4547.799 us; speedup 1.0000x reference)
//
#include <hip/hip_runtime.h>
#include <hip/hip_bf16.h>

// Problem constants
#define B    16
#define IC1  128
#define OC   256
#define ZD   64
#define H    64
#define W    64
#define HO   32
#define WO   32
#define NG   8
#define EPS  1e-5f

// Workspace layout (floats)
#define N_W1   (OC*IC1*9)        // 294912
#define N_W2   (OC*OC*9)         // 589824
#define N_WSC  (OC*IC1)          // 32768
#define OFF_W1   ((size_t)0)
#define OFF_W2   (OFF_W1 + (size_t)B*N_W1)
#define OFF_WSC  (OFF_W2 + (size_t)B*N_W2)
#define OFF_OUT1 (OFF_WSC + (size_t)B*N_WSC)
#define OFF_OUT2 (OFF_OUT1 + (size_t)B*OC*HO*WO)
#define OFF_STATS (OFF_OUT2 + (size_t)B*OC*HO*WO)

// ---------------------------------------------------------------------------
// Weight generation: out[b*N + n] = base_w[n] + head_b[n] + sum_k z[b,k]*head_w[n,k]
// Each thread handles 4 consecutive rows n (contiguous 256-float head_w read,
// float4 stores per b), all 16 batches. z staged in LDS, read as float4 broadcast.
// ---------------------------------------------------------------------------
__global__ void gen_w_kern(const float* __restrict__ hw, const float* __restrict__ hb,
                           const float* __restrict__ bw, const float* __restrict__ z,
                           float* __restrict__ out, int N) {
    __shared__ float zs[B * ZD];
    const int tid = threadIdx.x;
    for (int i = tid; i < B * ZD; i += 256) zs[i] = z[i];
    __syncthreads();

    const int n0 = (blockIdx.x * 256 + tid) * 4;
    if (n0 >= N) return;

    const float4* hw4 = (const float4*)(hw + (size_t)n0 * ZD);
    float4 b4  = *(const float4*)(bw + n0);
    float4 hb4 = *(const float4*)(hb + n0);
    float base0 = b4.x + hb4.x, base1 = b4.y + hb4.y, base2 = b4.z + hb4.z, base3 = b4.w + hb4.w;

    float acc[B][4];
    #pragma unroll
    for (int b = 0; b < B; ++b) { acc[b][0]=base0; acc[b][1]=base1; acc[b][2]=base2; acc[b][3]=base3; }

    #pragma unroll
    for (int k4 = 0; k4 < ZD/4; ++k4) {
        float4 w0 = hw4[0*16 + k4];
        float4 w1 = hw4[1*16 + k4];
        float4 w2 = hw4[2*16 + k4];
        float4 w3 = hw4[3*16 + k4];
        #pragma unroll
        for (int b = 0; b < B; ++b) {
            float4 zf = *(const float4*)&zs[b*ZD + k4*4];
            acc[b][0] += zf.x*w0.x + zf.y*w0.y + zf.z*w0.z + zf.w*w0.w;
            acc[b][1] += zf.x*w1.x + zf.y*w1.y + zf.z*w1.z + zf.w*w1.w;
            acc[b][2] += zf.x*w2.x + zf.y*w2.y + zf.z*w2.z + zf.w*w2.w;
            acc[b][3] += zf.x*w3.x + zf.y*w3.y + zf.z*w3.z + zf.w*w3.w;
        }
    }
    #pragma unroll
    for (int b = 0; b < B; ++b) {
        float4 o; o.x = acc[b][0]; o.y = acc[b][1]; o.z = acc[b][2]; o.w = acc[b][3];
        *(float4*)&out[(size_t)b * N + n0] = o;
    }
}

// ---------------------------------------------------------------------------
// Direct 3x3 conv, one thread per output element. Weights uniform per block
// (b, oc fixed) -> scalar loads. grid = (4, OC, B), block = 256 (8x32 of plane).
// ---------------------------------------------------------------------------
template<int IC, int IH, int STRIDE>
__global__ void conv3x3_kern(const float* __restrict__ in, const float* __restrict__ wts,
                             float* __restrict__ out) {
    const int b  = blockIdx.z;
    const int oc = blockIdx.y;
    const int p  = blockIdx.x * 256 + threadIdx.x;   // 0..1023
    const int y  = p >> 5;
    const int x  = p & 31;

    const float* wb  = wts + ((size_t)b * OC + oc) * IC * 9;
    const float* inb = in  + (size_t)b * IC * IH * IH;

    const int iy0 = y * STRIDE - 1;
    const int ix0 = x * STRIDE - 1;

    float acc = 0.f;
    for (int ic = 0; ic < IC; ++ic) {
        const float* ip = inb + (size_t)ic * IH * IH;
        const float* wp = wb + ic * 9;
        #pragma unroll
        for (int kh = 0; kh < 3; ++kh) {
            const int iy = iy0 + kh;
            if (iy < 0 || iy >= IH) continue;
            const float* row = ip + iy * IH;
            #pragma unroll
            for (int kw = 0; kw < 3; ++kw) {
                const int ix = ix0 + kw;
                float v = (ix >= 0 && ix < IH) ? row[ix] : 0.f;
                acc += wp[kh*3 + kw] * v;
            }
        }
    }
    out[((size_t)b * OC + oc) * (HO*WO) + p] = acc;
}

// ---------------------------------------------------------------------------
// GroupNorm pass. Group (b,g) = 32 contiguous channels = 32768 contiguous floats.
// gn_apply: normalize + affine + relu in place. gn_stats: store mean/rstd only.
// ---------------------------------------------------------------------------
__device__ inline void gn_reduce(float& s, float& s2, float* red) {
    #pragma unroll
    for (int off = 32; off > 0; off >>= 1) {
        s  += __shfl_down(s,  off);
        s2 += __shfl_down(s2, off);
    }
    const int wid = threadIdx.x >> 6, lane = threadIdx.x & 63;
    if (lane == 0) { red[wid] = s; red[4 + wid] = s2; }
    __syncthreads();
    if (threadIdx.x == 0) {
        s  = red[0] + red[1] + red[2] + red[3];
        s2 = red[4] + red[5] + red[6] + red[7];
    }
}

__global__ void gn_apply_relu_kern(float* __restrict__ data,
                                   const float* __restrict__ gamma,
                                   const float* __restrict__ beta) {
    const int bg = blockIdx.x;            // b*NG + g
    const int g  = bg & (NG - 1);
    float* base = data + (size_t)bg * 32768;
    float4* p4 = (float4*)base;

    float s = 0.f, s2 = 0.f;
    for (int i = threadIdx.x; i < 8192; i += 256) {
        float4 v = p4[i];
        s  += v.x + v.y + v.z + v.w;
        s2 += v.x*v.x + v.y*v.y + v.z*v.z + v.w*v.w;
    }
    __shared__ float red[8];
    __shared__ float smean, srstd;
    gn_reduce(s, s2, red);
    if (threadIdx.x == 0) {
        float mean = s * (1.0f / 32768.0f);
        float var  = s2 * (1.0f / 32768.0f) - mean * mean;
        smean = mean;
        srstd = rsqrtf(var + EPS);
    }
    __syncthreads();
    const float mean = smean, rstd = srstd;

    for (int i = threadIdx.x; i < 8192; i += 256) {
        const int c = g * 32 + (i >> 8);  // 256 float4 per channel
        const float ga = gamma[c] * rstd;
        const float be = beta[c] - mean * ga;
        float4 v = p4[i];
        v.x = fmaxf(v.x * ga + be, 0.f);
        v.y = fmaxf(v.y * ga + be, 0.f);
        v.z = fmaxf(v.z * ga + be, 0.f);
        v.w = fmaxf(v.w * ga + be, 0.f);
        p4[i] = v;
    }
}

__global__ void gn_stats_kern(const float* __restrict__ data, float* __restrict__ stats) {
    const int bg = blockIdx.x;
    const float4* p4 = (const float4*)(data + (size_t)bg * 32768);
    float s = 0.f, s2 = 0.f;
    for (int i = threadIdx.x; i < 8192; i += 256) {
        float4 v = p4[i];
        s  += v.x + v.y + v.z + v.w;
        s2 += v.x*v.x + v.y*v.y + v.z*v.z + v.w*v.w;
    }
    __shared__ float red[8];
    gn_reduce(s, s2, red);
    if (threadIdx.x == 0) {
        float mean = s * (1.0f / 32768.0f);
        float var  = s2 * (1.0f / 32768.0f) - mean * mean;
        stats[bg * 2 + 0] = mean;
        stats[bg * 2 + 1] = rsqrtf(var + EPS);
    }
}

// ---------------------------------------------------------------------------
// Final: 1x1 stride-2 shortcut conv + GN2 apply + add + relu.
// grid = (4, OC, B), block 256.
// ---------------------------------------------------------------------------
__global__ void final_kern(const float* __restrict__ out2, const float* __restrict__ x,
                           const float* __restrict__ wsc, const float* __restrict__ stats,
                           const float* __restrict__ gamma, const float* __restrict__ beta,
                           float* __restrict__ out) {
    const int b  = blockIdx.z;
    const int oc = blockIdx.y;
    const int p  = blockIdx.x * 256 + threadIdx.x;
    const int y  = p >> 5;
    const int xx = p & 31;

    const float* wp = wsc + ((size_t)b * OC + oc) * IC1;
    const float* xb = x + (size_t)b * IC1 * H * W;
    const int off = (2*y) * W + 2*xx;

    float acc = 0.f;
    for (int ic = 0; ic < IC1; ++ic)
        acc += wp[ic] * xb[(size_t)ic * H * W + off];

    const int g = oc >> 5;
    const float mean = stats[(b*NG + g)*2 + 0];
    const float rstd = stats[(b*NG + g)*2 + 1];
    const size_t idx = ((size_t)b * OC + oc) * (HO*WO) + p;
    float v = out2[idx];
    v = (v - mean) * rstd * gamma[oc] + beta[oc] + acc;
    out[idx] = fmaxf(v, 0.f);
}

// ---------------------------------------------------------------------------
extern "C" void kernel_launch(void* const* d_in, const int* in_sizes, int n_in,
                              void* d_out, int out_size, void* d_ws, size_t ws_size,
                              hipStream_t stream) {
    const float* x        = (const float*)d_in[0];
    const float* z        = (const float*)d_in[1];
    const float* base_w1  = (const float*)d_in[2];
    const float* head_w1  = (const float*)d_in[3];
    const float* head_b1  = (const float*)d_in[4];
    const float* gn_w1    = (const float*)d_in[5];
    const float* gn_b1    = (const float*)d_in[6];
    const float* base_w2  = (const float*)d_in[7];
    const float* head_w2  = (const float*)d_in[8];
    const float* head_b2  = (const float*)d_in[9];
    const float* gn_w2    = (const float*)d_in[10];
    const float* gn_b2    = (const float*)d_in[11];
    const float* base_wsc = (const float*)d_in[12];
    const float* head_wsc = (const float*)d_in[13];
    const float* head_bsc = (const float*)d_in[14];

    float* ws    = (float*)d_ws;
    float* w1    = ws + OFF_W1;
    float* w2    = ws + OFF_W2;
    float* wsc   = ws + OFF_WSC;
    float* out1  = ws + OFF_OUT1;
    float* out2  = ws + OFF_OUT2;
    float* stats = ws + OFF_STATS;
    float* out   = (float*)d_out;

    // Weight generation (each block: 1024 rows)
    gen_w_kern<<<N_W1 / 1024, 256, 0, stream>>>(head_w1, head_b1, base_w1, z, w1, N_W1);
    gen_w_kern<<<N_W2 / 1024, 256, 0, stream>>>(head_w2, head_b2, base_w2, z, w2, N_W2);
    gen_w_kern<<<N_WSC / 1024, 256, 0, stream>>>(head_wsc, head_bsc, base_wsc, z, wsc, N_WSC);

    // conv1 (stride 2) -> out1
    conv3x3_kern<IC1, H, 2><<<dim3(4, OC, B), 256, 0, stream>>>(x, w1, out1);
    // GN1 + relu in place
    gn_apply_relu_kern<<<B * NG, 256, 0, stream>>>(out1, gn_w1, gn_b1);
    // conv2 (stride 1) -> out2
    conv3x3_kern<OC, HO, 1><<<dim3(4, OC, B), 256, 0, stream>>>(out1, w2, out2);
    // GN2 stats
    gn_stats_kern<<<B * NG, 256, 0, stream>>>(out2, stats);
    // shortcut conv + GN2 apply + add + relu
    final_kern<<<dim3(4, OC, B), 256, 0, stream>>>(out2, x, wsc, stats, gn_w2, gn_b2, out);
}

// Round 2
// 916.056 us; speedup vs baseline: 4.9645x; 4.9645x over previous
//
#include <hip/hip_runtime.h>
#include <hip/hip_bf16.h>

typedef unsigned short u16;

#define B_   16
#define OC   256
#define ZD   64
#define NG_  8
#define EPS  1e-5f

typedef __attribute__((ext_vector_type(8))) __bf16 bf16x8;
typedef __attribute__((ext_vector_type(4))) float f32x4;
typedef __attribute__((ext_vector_type(8))) u16 ushort8;
typedef __attribute__((ext_vector_type(4))) u16 ushort4v;

// Workspace layout (bytes)
#define OFF_A1   ((size_t)0)            // 16*256*1152*2 = 9,437,184   (later reused as Bsc)
#define OFF_A2   ((size_t)9437184)      // 16*256*2304*2 = 18,874,368
#define OFF_ASC  ((size_t)28311552)     // 16*256*128*2  = 1,048,576
#define OFF_BBIG ((size_t)29360128)     // 16*1024*2304*2 = 75,497,472 (B1 then B2)
#define OFF_O12  ((size_t)104857600)    // 16*256*1024*4 = 16,777,216  (out1 then out2)
#define OFF_ST1  ((size_t)121634816)
#define OFF_ST2  ((size_t)121635840)

__device__ __forceinline__ u16 f2bf(float f) {
    union { float f; unsigned u; } x; x.f = f;
    unsigned r = x.u + 0x7fffu + ((x.u >> 16) & 1u);   // RNE
    return (u16)(r >> 16);
}

#define GLD16(gp, lp) __builtin_amdgcn_global_load_lds(                    \
        (const __attribute__((address_space(1))) void*)(gp),               \
        (__attribute__((address_space(3))) void*)(lp), 16, 0, 0)

// ---------------------------------------------------------------------------
// Weight gen: A[b][oc][d*ICk+ic] = bf16( base_w[oc,ic,d] + head_b[n] + z[b]·head_w[n] )
// n = (oc*ICk+ic)*KD + d. Thread: (oc, d, 4 consecutive ic) for all 16 batches.
// ---------------------------------------------------------------------------
template<int ICk, int KD>
__global__ void gen_w_kern(const float* __restrict__ hw, const float* __restrict__ hb,
                           const float* __restrict__ bw, const float* __restrict__ z,
                           u16* __restrict__ A) {
    __shared__ float zs[B_ * ZD];
    for (int i = threadIdx.x; i < B_ * ZD; i += 256) zs[i] = z[i];
    __syncthreads();

    const int gtid = blockIdx.x * 256 + threadIdx.x;
    const int nseg = ICk / 4;
    const int ic0 = (gtid % nseg) * 4;
    int t = gtid / nseg;
    const int d  = t % KD;
    const int oc = t / KD;
    const size_t nb = ((size_t)oc * ICk + ic0) * KD + d;

    float accv[B_][4];
    #pragma unroll
    for (int i = 0; i < 4; ++i) {
        float base = bw[nb + (size_t)i * KD] + hb[nb + (size_t)i * KD];
        #pragma unroll
        for (int b = 0; b < B_; ++b) accv[b][i] = base;
    }
    const float* r0 = hw + nb * ZD;
    for (int k4 = 0; k4 < ZD / 4; ++k4) {
        float4 w[4];
        #pragma unroll
        for (int i = 0; i < 4; ++i)
            w[i] = *(const float4*)(r0 + (size_t)i * KD * ZD + k4 * 4);
        #pragma unroll
        for (int b = 0; b < B_; ++b) {
            float4 zf = *(const float4*)&zs[b * ZD + k4 * 4];
            #pragma unroll
            for (int i = 0; i < 4; ++i)
                accv[b][i] += zf.x * w[i].x + zf.y * w[i].y + zf.z * w[i].z + zf.w * w[i].w;
        }
    }
    const int K = ICk * KD;
    #pragma unroll
    for (int b = 0; b < B_; ++b) {
        ushort4v o;
        o.x = f2bf(accv[b][0]); o.y = f2bf(accv[b][1]);
        o.z = f2bf(accv[b][2]); o.w = f2bf(accv[b][3]);
        *(ushort4v*)&A[((size_t)b * OC + oc) * K + d * ICk + ic0] = o;
    }
}

// ---------------------------------------------------------------------------
// im2col to bf16 [b][n=1024][k=d*IC+ic]; optional fused GN+ReLU (pad zeros AFTER GN).
// Thread: one 8-ushort (16B) chunk along ic.
// ---------------------------------------------------------------------------
template<int IC, int IH, int STRIDE, int KD, bool GN>
__global__ void im2col_kern(const float* __restrict__ in, u16* __restrict__ Bm,
                            const float* __restrict__ stats,
                            const float* __restrict__ gamma,
                            const float* __restrict__ beta) {
    const int gtid = blockIdx.x * 256 + threadIdx.x;
    const int segs = IC / 8;
    const int ic0 = (gtid % segs) * 8;
    int t = gtid / segs;
    const int d = t % KD; t /= KD;
    const int n = t & 1023;
    const int b = t >> 10;
    const int y = n >> 5, x = n & 31;
    const int iy = STRIDE * y + (KD == 9 ? d / 3 - 1 : 0);
    const int ix = STRIDE * x + (KD == 9 ? d % 3 - 1 : 0);
    const bool inb = (iy >= 0 && iy < IH && ix >= 0 && ix < IH);
    const float* src = in + (((size_t)b * IC + ic0) * IH + iy) * IH + ix;

    float mean = 0.f, rstd = 0.f;
    if (GN) {
        const int g = ic0 >> 5;
        mean = stats[(b * NG_ + g) * 2 + 0];
        rstd = stats[(b * NG_ + g) * 2 + 1];
    }
    ushort8 o;
    #pragma unroll
    for (int j = 0; j < 8; ++j) {
        float v = 0.f;
        if (inb) {
            v = src[(size_t)j * IH * IH];
            if (GN) v = fmaxf((v - mean) * rstd * gamma[ic0 + j] + beta[ic0 + j], 0.f);
        }
        o[j] = f2bf(v);
    }
    const int K = KD * IC;
    *(ushort8*)&Bm[((size_t)b * 1024 + n) * K + d * IC + ic0] = o;
}

// ---------------------------------------------------------------------------
// GroupNorm stats: one block per (b,g); group = 32768 contiguous floats.
// ---------------------------------------------------------------------------
__global__ void gn_stats_kern(const float* __restrict__ data, float* __restrict__ stats) {
    const int bg = blockIdx.x;
    const float4* p4 = (const float4*)(data + (size_t)bg * 32768);
    float s = 0.f, s2 = 0.f;
    for (int i = threadIdx.x; i < 8192; i += 256) {
        float4 v = p4[i];
        s  += v.x + v.y + v.z + v.w;
        s2 += v.x*v.x + v.y*v.y + v.z*v.z + v.w*v.w;
    }
    __shared__ float red[8];
    #pragma unroll
    for (int off = 32; off > 0; off >>= 1) {
        s  += __shfl_down(s,  off);
        s2 += __shfl_down(s2, off);
    }
    const int wid = threadIdx.x >> 6, lane = threadIdx.x & 63;
    if (lane == 0) { red[wid] = s; red[4 + wid] = s2; }
    __syncthreads();
    if (threadIdx.x == 0) {
        s  = red[0] + red[1] + red[2] + red[3];
        s2 = red[4] + red[5] + red[6] + red[7];
        float mean = s * (1.0f / 32768.0f);
        float var  = s2 * (1.0f / 32768.0f) - mean * mean;
        stats[bg * 2 + 0] = mean;
        stats[bg * 2 + 1] = rsqrtf(var + EPS);
    }
}

// ---------------------------------------------------------------------------
// MFMA GEMM: per batch, C[256,1024] (+)= A[256,K] * B[1024,K]^T  (both [row][k] bf16).
// 128x128 block tile, 4 waves of 64x64, 16x16x32 bf16 MFMA, global_load_lds staging.
// S-way K-split over blockIdx.z; EPI=0: atomicAdd into zeroed C.
// EPI=1 (S=1): fused GN2-apply + add + ReLU -> final output.
// ---------------------------------------------------------------------------
template<int K, int S, int EPI>
__global__ __launch_bounds__(256, 2)
void gemm_kern(const u16* __restrict__ A,    // [B][256][K]
               const u16* __restrict__ Bm,   // [B][1024][K]
               float* __restrict__ C,
               const float* __restrict__ D2,
               const float* __restrict__ stats,
               const float* __restrict__ gamma,
               const float* __restrict__ beta) {
    __shared__ __align__(16) u16 As[128 * 32];
    __shared__ __align__(16) u16 Bs[128 * 32];

    const int bz = blockIdx.z;
    const int b  = bz / S;
    const int ks = bz % S;
    const int m0 = blockIdx.y * 128;
    const int n0 = blockIdx.x * 128;
    const int tid  = threadIdx.x;
    const int lane = tid & 63;
    const int wid  = tid >> 6;           // 0..3
    const int wm = (wid >> 1) * 64;
    const int wn = (wid & 1) * 64;
    const int lr  = lane >> 2;           // staging row within 16-row group
    const int lcb = (lane & 3) * 16;     // staging byte col within 64B row

    const u16* Ab = A  + ((size_t)b * OC   + m0) * K;
    const u16* Bb = Bm + ((size_t)b * 1024 + n0) * K;

    const f32x4 fzero = {0.f, 0.f, 0.f, 0.f};
    f32x4 acc[4][4];
    #pragma unroll
    for (int i = 0; i < 4; ++i)
        #pragma unroll
        for (int j = 0; j < 4; ++j) acc[i][j] = fzero;

    const int KC   = K / S;
    const int kbeg = ks * KC;
    const int q8  = (lane >> 4) * 8;
    const int l16 = lane & 15;

    for (int k0 = kbeg; k0 < kbeg + KC; k0 += 32) {
        __syncthreads();
        // stage 128x32 A and 128x32 B (16 KB): 4 x global_load_lds_dwordx4 per wave
        GLD16((const char*)(Ab + (size_t)(wid * 16 + lr) * K + k0) + lcb,
              &As[(wid * 16) * 32]);
        GLD16((const char*)(Ab + (size_t)(64 + wid * 16 + lr) * K + k0) + lcb,
              &As[(64 + wid * 16) * 32]);
        GLD16((const char*)(Bb + (size_t)(wid * 16 + lr) * K + k0) + lcb,
              &Bs[(wid * 16) * 32]);
        GLD16((const char*)(Bb + (size_t)(64 + wid * 16 + lr) * K + k0) + lcb,
              &Bs[(64 + wid * 16) * 32]);
        __syncthreads();

        bf16x8 af[4], bfr[4];
        #pragma unroll
        for (int i = 0; i < 4; ++i)
            af[i] = *(const bf16x8*)&As[(wm + i * 16 + l16) * 32 + q8];
        #pragma unroll
        for (int j = 0; j < 4; ++j)
            bfr[j] = *(const bf16x8*)&Bs[(wn + j * 16 + l16) * 32 + q8];
        #pragma unroll
        for (int i = 0; i < 4; ++i)
            #pragma unroll
            for (int j = 0; j < 4; ++j)
                acc[i][j] = __builtin_amdgcn_mfma_f32_16x16x32_bf16(af[i], bfr[j], acc[i][j], 0, 0, 0);
    }

    // epilogue: C/D layout col = lane&15, row = (lane>>4)*4 + r
    const int q4 = (lane >> 4) * 4;
    #pragma unroll
    for (int i = 0; i < 4; ++i) {
        #pragma unroll
        for (int j = 0; j < 4; ++j) {
            #pragma unroll
            for (int r = 0; r < 4; ++r) {
                const int ml = wm + i * 16 + q4 + r;
                const int nl = wn + j * 16 + l16;
                const size_t idx = ((size_t)b * OC + m0 + ml) * 1024 + n0 + nl;
                if (EPI == 0) {
                    atomicAdd(&C[idx], acc[i][j][r]);
                } else {
                    const int oc = m0 + ml;
                    const int g  = oc >> 5;
                    const float mean = stats[(b * NG_ + g) * 2 + 0];
                    const float rstd = stats[(b * NG_ + g) * 2 + 1];
                    float v = (D2[idx] - mean) * rstd * gamma[oc] + beta[oc] + acc[i][j][r];
                    C[idx] = fmaxf(v, 0.f);
                }
            }
        }
    }
}

// ---------------------------------------------------------------------------
extern "C" void kernel_launch(void* const* d_in, const int* in_sizes, int n_in,
                              void* d_out, int out_size, void* d_ws, size_t ws_size,
                              hipStream_t stream) {
    const float* x        = (const float*)d_in[0];
    const float* z        = (const float*)d_in[1];
    const float* base_w1  = (const float*)d_in[2];
    const float* head_w1  = (const float*)d_in[3];
    const float* head_b1  = (const float*)d_in[4];
    const float* gn_w1    = (const float*)d_in[5];
    const float* gn_b1    = (const float*)d_in[6];
    const float* base_w2  = (const float*)d_in[7];
    const float* head_w2  = (const float*)d_in[8];
    const float* head_b2  = (const float*)d_in[9];
    const float* gn_w2    = (const float*)d_in[10];
    const float* gn_b2    = (const float*)d_in[11];
    const float* base_wsc = (const float*)d_in[12];
    const float* head_wsc = (const float*)d_in[13];
    const float* head_bsc = (const float*)d_in[14];

    char* ws = (char*)d_ws;
    u16*  A1   = (u16*)(ws + OFF_A1);
    u16*  A2   = (u16*)(ws + OFF_A2);
    u16*  Asc  = (u16*)(ws + OFF_ASC);
    u16*  Bbig = (u16*)(ws + OFF_BBIG);
    u16*  Bsc  = (u16*)(ws + OFF_A1);   // reuses A1 region after gemm1
    float* o12 = (float*)(ws + OFF_O12);
    float* st1 = (float*)(ws + OFF_ST1);
    float* st2 = (float*)(ws + OFF_ST2);
    float* out = (float*)d_out;

    // zero out1 accumulator
    hipMemsetAsync(o12, 0, (size_t)16777216, stream);

    // hyper-weight generation (bf16, GEMM-ready layout)
    gen_w_kern<128, 9><<<288, 256, 0, stream>>>(head_w1, head_b1, base_w1, z, A1);
    gen_w_kern<256, 9><<<576, 256, 0, stream>>>(head_w2, head_b2, base_w2, z, A2);
    gen_w_kern<128, 1><<<32,  256, 0, stream>>>(head_wsc, head_bsc, base_wsc, z, Asc);

    // conv1 = GEMM(A1, im2col(x))
    im2col_kern<128, 64, 2, 9, false><<<9216, 256, 0, stream>>>(x, Bbig, nullptr, nullptr, nullptr);
    gemm_kern<1152, 2, 0><<<dim3(8, 2, 32), 256, 0, stream>>>(A1, Bbig, o12,
                                                              nullptr, nullptr, nullptr, nullptr);
    gn_stats_kern<<<B_ * NG_, 256, 0, stream>>>(o12, st1);

    // shortcut im2col (A1 now dead -> reuse its region)
    im2col_kern<128, 64, 2, 1, false><<<1024, 256, 0, stream>>>(x, Bsc, nullptr, nullptr, nullptr);

    // conv2 = GEMM(A2, im2col(GN1+relu(out1)))  [GN fused into im2col]
    im2col_kern<256, 32, 1, 9, true><<<18432, 256, 0, stream>>>(o12, Bbig, st1, gn_w1, gn_b1);
    hipMemsetAsync(o12, 0, (size_t)16777216, stream);   // o12 becomes out2 accumulator
    gemm_kern<2304, 2, 0><<<dim3(8, 2, 32), 256, 0, stream>>>(A2, Bbig, o12,
                                                              nullptr, nullptr, nullptr, nullptr);
    gn_stats_kern<<<B_ * NG_, 256, 0, stream>>>(o12, st2);

    // shortcut GEMM with fused GN2-apply + add + relu epilogue
    gemm_kern<128, 1, 1><<<dim3(8, 2, 16), 256, 0, stream>>>(Asc, Bsc, out,
                                                             o12, st2, gn_w2, gn_b2);
}

// Round 3
// 611.551 us; speedup vs baseline: 7.4365x; 1.4979x over previous
//
#include <hip/hip_runtime.h>
#include <hip/hip_bf16.h>

typedef unsigned short u16;

#define B_   16
#define OC   256
#define ZD   64
#define NG_  8
#define EPS  1e-5f

typedef __attribute__((ext_vector_type(8))) __bf16 bf16x8;
typedef __attribute__((ext_vector_type(4))) float f32x4;
typedef __attribute__((ext_vector_type(8))) u16 ushort8;

// Workspace layout (bytes), total ~71.3 MB
#define OFF_XT  ((size_t)0)          // xT  bf16 [16][4096][128] = 16,777,216
#define OFF_A1  ((size_t)16777216)   // A1  bf16 [16][256][1152] =  9,437,184
#define OFF_A2  ((size_t)26214400)   // A2  bf16 [16][256][2304] = 18,874,368
#define OFF_ASC ((size_t)45088768)   // Asc bf16 [16][256][128]  =  1,048,576
#define OFF_O12 ((size_t)46137344)   // out1/out2 fp32 [16][1024][256] = 16,777,216
#define OFF_YT  ((size_t)62914560)   // yT  bf16 [16][1024][256] =  8,388,608
#define OFF_ST1 ((size_t)71303168)   // 1 KB
#define OFF_ST2 ((size_t)71304192)   // 1 KB
#define OFF_ZP  ((size_t)71305216)   // 512 B zero page

__device__ __forceinline__ u16 f2bf(float f) {
    union { float f; unsigned u; } x; x.f = f;
    unsigned r = x.u + 0x7fffu + ((x.u >> 16) & 1u);   // RNE
    return (u16)(r >> 16);
}

#define GLD16(gp, lp) __builtin_amdgcn_global_load_lds(                    \
        (const __attribute__((address_space(1))) void*)(gp),               \
        (__attribute__((address_space(3))) void*)(lp), 16, 0, 0)

// ---------------------------------------------------------------------------
// x NCHW fp32 -> xT [b][n=4096][ic=128] bf16. Register transpose:
// thread owns one n, 32 ic; scalar loads lane-coalesced, 4x ushort8 stores.
// ---------------------------------------------------------------------------
__global__ void transpose_x_kern(const float* __restrict__ x, u16* __restrict__ xT) {
    const int b = blockIdx.z, ic0 = blockIdx.y * 32;
    const int n = blockIdx.x * 256 + threadIdx.x;
    const float* xp = x + ((size_t)b * 128 + ic0) * 4096 + n;
    u16* op = xT + ((size_t)b * 4096 + n) * 128 + ic0;
    float v[32];
    #pragma unroll
    for (int i = 0; i < 32; ++i) v[i] = xp[(size_t)i * 4096];
    #pragma unroll
    for (int c = 0; c < 4; ++c) {
        ushort8 o;
        #pragma unroll
        for (int j = 0; j < 8; ++j) o[j] = f2bf(v[c * 8 + j]);
        *(ushort8*)(op + c * 8) = o;
    }
}

// ---------------------------------------------------------------------------
// Weight gen, read-coalesced: thread owns 2 CONSECUTIVE head_w rows (512 B,
// lane stride 512 B -> 32 KB wave working set, L1-resident, no over-fetch).
// Output k-index = d*ICk+ic (scattered cheap bf16 scalar stores).
// ---------------------------------------------------------------------------
template<int ICk, int KD>
__global__ void gen_w_kern(const float* __restrict__ hw, const float* __restrict__ hb,
                           const float* __restrict__ bw, const float* __restrict__ z,
                           u16* __restrict__ A) {
    __shared__ float zs[B_ * ZD];
    for (int i = threadIdx.x; i < B_ * ZD; i += 256) zs[i] = z[i];
    __syncthreads();

    const int n0 = (blockIdx.x * 256 + threadIdx.x) * 2;
    const float4* r0 = (const float4*)(hw + (size_t)n0 * ZD);
    const float4* r1 = (const float4*)(hw + (size_t)(n0 + 1) * ZD);

    float a[2][B_];
    {
        float b0 = bw[n0] + hb[n0];
        float b1 = bw[n0 + 1] + hb[n0 + 1];
        #pragma unroll
        for (int b = 0; b < B_; ++b) { a[0][b] = b0; a[1][b] = b1; }
    }
    #pragma unroll
    for (int k4 = 0; k4 < 16; ++k4) {
        float4 w0 = r0[k4], w1 = r1[k4];
        #pragma unroll
        for (int b = 0; b < B_; ++b) {
            float4 zf = *(const float4*)&zs[b * ZD + k4 * 4];
            a[0][b] += zf.x * w0.x + zf.y * w0.y + zf.z * w0.z + zf.w * w0.w;
            a[1][b] += zf.x * w1.x + zf.y * w1.y + zf.z * w1.z + zf.w * w1.w;
        }
    }
    const int K = ICk * KD;
    #pragma unroll
    for (int ri = 0; ri < 2; ++ri) {
        const int n  = n0 + ri;
        const int oc = n / (ICk * KD);
        const int r2 = n % (ICk * KD);
        const int ic = r2 / KD, dd = r2 % KD;
        const size_t kidx = (size_t)dd * ICk + ic;
        #pragma unroll
        for (int b = 0; b < B_; ++b)
            A[((size_t)b * OC + oc) * K + kidx] = f2bf(a[ri][b]);
    }
}

// ---------------------------------------------------------------------------
// GroupNorm stats on NHWC out [b][1024][256]: block per (b,g); cols g*32..+32.
// ---------------------------------------------------------------------------
__global__ void gn_stats_kern(const float* __restrict__ o1, float* __restrict__ stats) {
    const int b = blockIdx.x >> 3, g = blockIdx.x & 7;
    const int t = threadIdx.x;
    float s = 0.f, s2 = 0.f;
    for (int it = 0; it < 32; ++it) {
        const int n = it * 32 + (t >> 3);
        float4 v = *(const float4*)&o1[((size_t)b * 1024 + n) * 256 + g * 32 + (t & 7) * 4];
        s  += v.x + v.y + v.z + v.w;
        s2 += v.x*v.x + v.y*v.y + v.z*v.z + v.w*v.w;
    }
    __shared__ float red[8];
    #pragma unroll
    for (int off = 32; off > 0; off >>= 1) {
        s  += __shfl_down(s,  off);
        s2 += __shfl_down(s2, off);
    }
    const int wid = t >> 6, lane = t & 63;
    if (lane == 0) { red[wid] = s; red[4 + wid] = s2; }
    __syncthreads();
    if (t == 0) {
        s  = red[0] + red[1] + red[2] + red[3];
        s2 = red[4] + red[5] + red[6] + red[7];
        float mean = s * (1.0f / 32768.0f);
        float var  = s2 * (1.0f / 32768.0f) - mean * mean;
        stats[blockIdx.x * 2 + 0] = mean;
        stats[blockIdx.x * 2 + 1] = rsqrtf(var + EPS);
    }
}

// ---------------------------------------------------------------------------
// GN1 apply + ReLU + bf16: out1 [b][n][256] fp32 -> yT [b][n][256] bf16.
// ---------------------------------------------------------------------------
__global__ void gn_apply_kern(const float* __restrict__ o1, const float* __restrict__ stats,
                              const float* __restrict__ gamma, const float* __restrict__ beta,
                              u16* __restrict__ yT) {
    const int gtid = blockIdx.x * 256 + threadIdx.x;
    const int c8 = gtid & 31;
    const int n  = (gtid >> 5) & 1023;
    const int b  = gtid >> 15;
    const int g  = c8 >> 2;
    const float mean = stats[(b * NG_ + g) * 2 + 0];
    const float rstd = stats[(b * NG_ + g) * 2 + 1];
    const float* src = o1 + ((size_t)b * 1024 + n) * 256 + c8 * 8;
    float4 v0 = *(const float4*)src, v1 = *(const float4*)(src + 4);
    float4 g0 = *(const float4*)(gamma + c8 * 8), g1 = *(const float4*)(gamma + c8 * 8 + 4);
    float4 b0 = *(const float4*)(beta  + c8 * 8), b1 = *(const float4*)(beta  + c8 * 8 + 4);
    ushort8 o;
    o[0] = f2bf(fmaxf((v0.x - mean) * rstd * g0.x + b0.x, 0.f));
    o[1] = f2bf(fmaxf((v0.y - mean) * rstd * g0.y + b0.y, 0.f));
    o[2] = f2bf(fmaxf((v0.z - mean) * rstd * g0.z + b0.z, 0.f));
    o[3] = f2bf(fmaxf((v0.w - mean) * rstd * g0.w + b0.w, 0.f));
    o[4] = f2bf(fmaxf((v1.x - mean) * rstd * g1.x + b1.x, 0.f));
    o[5] = f2bf(fmaxf((v1.y - mean) * rstd * g1.y + b1.y, 0.f));
    o[6] = f2bf(fmaxf((v1.z - mean) * rstd * g1.z + b1.z, 0.f));
    o[7] = f2bf(fmaxf((v1.w - mean) * rstd * g1.w + b1.w, 0.f));
    *(ushort8*)(yT + ((size_t)b * 1024 + n) * 256 + c8 * 8) = o;
}

// ---------------------------------------------------------------------------
// Implicit-im2col MFMA conv GEMM.
// D[b][n=spatial 1024][oc=256] (+)= sum_k F_row(m(n,d))[ic] * Wm[b][oc][d*IC+ic]
// F: features [b][IH*IH][IC] bf16 (NHWC). Border rows -> 512B zero page.
// a-frag = spatial rows, b-frag = weight rows => D rows = spatial.
// S-way split over whole taps (KD/S per split). EPI=0: atomicAdd to zeroed C.
// EPI=1: fused GN2-apply(D2) + add + ReLU -> NCHW out (float4 along n).
// ---------------------------------------------------------------------------
template<int IC, int IH, int STRIDE, int KD, int S, int EPI>
__global__ __launch_bounds__(256, 2)
void conv_gemm(const u16* __restrict__ F, const u16* __restrict__ Wm,
               float* __restrict__ C, const u16* __restrict__ zp,
               const float* __restrict__ D2, const float* __restrict__ stats,
               const float* __restrict__ gamma, const float* __restrict__ beta) {
    constexpr int K   = IC * KD;
    constexpr int PAD = (KD == 9) ? 1 : 0;
    constexpr int DPS = KD / S;
    __shared__ __align__(16) u16 As[128 * 32];
    __shared__ __align__(16) u16 Bs[128 * 32];

    const int b  = blockIdx.z / S;
    const int ks = blockIdx.z % S;
    const int m0 = blockIdx.y * 128;     // spatial
    const int n0 = blockIdx.x * 128;     // oc
    const int tid = threadIdx.x, lane = tid & 63, wid = tid >> 6;
    const int wm = (wid >> 1) * 64, wn = (wid & 1) * 64;
    const int lr  = lane >> 2;
    const int lc  = (lane & 3) * 8;      // u16 offset within 64B row segment
    const int l16 = lane & 15, q8 = (lane >> 4) * 8;

    // spatial coords of this lane's two A-staging rows
    const int ra0 = m0 + wid * 16 + lr, ra1 = ra0 + 64;
    const int y0 = ra0 >> 5, x0 = ra0 & 31;
    const int y1 = ra1 >> 5, x1 = ra1 & 31;
    const size_t fb = (size_t)b * IH * IH * IC;

    const u16* q0 = Wm + ((size_t)b * OC + n0 + wid * 16 + lr) * K + lc;
    const u16* q1 = q0 + (size_t)64 * K;

    const f32x4 fzero = {0.f, 0.f, 0.f, 0.f};
    f32x4 acc[4][4];
    #pragma unroll
    for (int i = 0; i < 4; ++i)
        #pragma unroll
        for (int j = 0; j < 4; ++j) acc[i][j] = fzero;

    for (int di = 0; di < DPS; ++di) {
        const int d  = ks * DPS + di;
        const int dy = (KD == 9) ? d / 3 : 0;
        const int dx = (KD == 9) ? d % 3 : 0;
        const int iy0 = STRIDE * y0 + dy - PAD, ix0 = STRIDE * x0 + dx - PAD;
        const int iy1 = STRIDE * y1 + dy - PAD, ix1 = STRIDE * x1 + dx - PAD;
        const bool v0 = ((unsigned)iy0 < (unsigned)IH) && ((unsigned)ix0 < (unsigned)IH);
        const bool v1 = ((unsigned)iy1 < (unsigned)IH) && ((unsigned)ix1 < (unsigned)IH);
        const u16* P0 = v0 ? F + fb + ((size_t)iy0 * IH + ix0) * IC + lc : zp + lc;
        const u16* P1 = v1 ? F + fb + ((size_t)iy1 * IH + ix1) * IC + lc : zp + lc;
        const int kd = d * IC;
        for (int ic0 = 0; ic0 < IC; ic0 += 32) {
            __syncthreads();
            GLD16(P0 + ic0,      &As[(wid * 16) * 32]);
            GLD16(P1 + ic0,      &As[(64 + wid * 16) * 32]);
            GLD16(q0 + kd + ic0, &Bs[(wid * 16) * 32]);
            GLD16(q1 + kd + ic0, &Bs[(64 + wid * 16) * 32]);
            __syncthreads();

            bf16x8 af[4], bfr[4];
            #pragma unroll
            for (int i = 0; i < 4; ++i)
                af[i] = *(const bf16x8*)&As[(wm + i * 16 + l16) * 32 + q8];
            #pragma unroll
            for (int j = 0; j < 4; ++j)
                bfr[j] = *(const bf16x8*)&Bs[(wn + j * 16 + l16) * 32 + q8];
            #pragma unroll
            for (int i = 0; i < 4; ++i)
                #pragma unroll
                for (int j = 0; j < 4; ++j)
                    acc[i][j] = __builtin_amdgcn_mfma_f32_16x16x32_bf16(af[i], bfr[j], acc[i][j], 0, 0, 0);
        }
    }

    const int q4 = (lane >> 4) * 4;
    if (EPI == 0) {
        #pragma unroll
        for (int i = 0; i < 4; ++i)
            #pragma unroll
            for (int j = 0; j < 4; ++j)
                #pragma unroll
                for (int r = 0; r < 4; ++r) {
                    const int ml = m0 + wm + i * 16 + q4 + r;
                    const int nl = n0 + wn + j * 16 + l16;
                    atomicAdd(&C[((size_t)b * 1024 + ml) * 256 + nl], acc[i][j][r]);
                }
    } else {
        #pragma unroll
        for (int j = 0; j < 4; ++j) {
            const int oc = n0 + wn + j * 16 + l16;
            const int gg = oc >> 5;
            const float mean = stats[(b * NG_ + gg) * 2 + 0];
            const float rstd = stats[(b * NG_ + gg) * 2 + 1];
            const float ga = gamma[oc] * rstd;
            const float bb = beta[oc] - mean * ga;
            #pragma unroll
            for (int i = 0; i < 4; ++i) {
                const int nb = m0 + wm + i * 16 + q4;
                float4 o;
                #pragma unroll
                for (int r = 0; r < 4; ++r) {
                    float v = D2[((size_t)b * 1024 + nb + r) * 256 + oc] * ga + bb + acc[i][j][r];
                    ((float*)&o)[r] = fmaxf(v, 0.f);
                }
                *(float4*)&C[((size_t)b * OC + oc) * 1024 + nb] = o;
            }
        }
    }
}

// ---------------------------------------------------------------------------
extern "C" void kernel_launch(void* const* d_in, const int* in_sizes, int n_in,
                              void* d_out, int out_size, void* d_ws, size_t ws_size,
                              hipStream_t stream) {
    const float* x        = (const float*)d_in[0];
    const float* z        = (const float*)d_in[1];
    const float* base_w1  = (const float*)d_in[2];
    const float* head_w1  = (const float*)d_in[3];
    const float* head_b1  = (const float*)d_in[4];
    const float* gn_w1    = (const float*)d_in[5];
    const float* gn_b1    = (const float*)d_in[6];
    const float* base_w2  = (const float*)d_in[7];
    const float* head_w2  = (const float*)d_in[8];
    const float* head_b2  = (const float*)d_in[9];
    const float* gn_w2    = (const float*)d_in[10];
    const float* gn_b2    = (const float*)d_in[11];
    const float* base_wsc = (const float*)d_in[12];
    const float* head_wsc = (const float*)d_in[13];
    const float* head_bsc = (const float*)d_in[14];

    char* ws = (char*)d_ws;
    u16*   xT  = (u16*)(ws + OFF_XT);
    u16*   A1  = (u16*)(ws + OFF_A1);
    u16*   A2  = (u16*)(ws + OFF_A2);
    u16*   Asc = (u16*)(ws + OFF_ASC);
    float* o12 = (float*)(ws + OFF_O12);
    u16*   yT  = (u16*)(ws + OFF_YT);
    float* st1 = (float*)(ws + OFF_ST1);
    float* st2 = (float*)(ws + OFF_ST2);
    u16*   zp  = (u16*)(ws + OFF_ZP);
    float* out = (float*)d_out;

    hipMemsetAsync(zp, 0, 512, stream);
    hipMemsetAsync(o12, 0, (size_t)16777216, stream);

    // x -> NHWC bf16
    transpose_x_kern<<<dim3(16, 4, 16), 256, 0, stream>>>(x, xT);

    // hyper-weight generation
    gen_w_kern<128, 9><<<576,  256, 0, stream>>>(head_w1, head_b1, base_w1, z, A1);
    gen_w_kern<256, 9><<<1152, 256, 0, stream>>>(head_w2, head_b2, base_w2, z, A2);
    gen_w_kern<128, 1><<<64,   256, 0, stream>>>(head_wsc, head_bsc, base_wsc, z, Asc);

    // conv1 (3x3 s2) implicit GEMM -> out1 [b][n][oc]
    conv_gemm<128, 64, 2, 9, 3, 0><<<dim3(2, 8, 48), 256, 0, stream>>>(
        xT, A1, o12, zp, nullptr, nullptr, nullptr, nullptr);
    gn_stats_kern<<<B_ * NG_, 256, 0, stream>>>(o12, st1);
    gn_apply_kern<<<2048, 256, 0, stream>>>(o12, st1, gn_w1, gn_b1, yT);

    // conv2 (3x3 s1) implicit GEMM -> out2 [b][n][oc]
    hipMemsetAsync(o12, 0, (size_t)16777216, stream);
    conv_gemm<256, 32, 1, 9, 3, 0><<<dim3(2, 8, 48), 256, 0, stream>>>(
        yT, A2, o12, zp, nullptr, nullptr, nullptr, nullptr);
    gn_stats_kern<<<B_ * NG_, 256, 0, stream>>>(o12, st2);

    // shortcut (1x1 s2) GEMM + fused GN2-apply + add + ReLU -> NCHW out
    conv_gemm<128, 64, 2, 1, 1, 1><<<dim3(2, 8, 16), 256, 0, stream>>>(
        xT, Asc, out, zp, o12, st2, gn_w2, gn_b2);
}

// Round 4
// 537.928 us; speedup vs baseline: 8.4543x; 1.1369x over previous
//
#include <hip/hip_runtime.h>
#include <hip/hip_bf16.h>

typedef unsigned short u16;

#define B_   16
#define OC   256
#define ZD   64
#define NG_  8
#define EPS  1e-5f

typedef __attribute__((ext_vector_type(8))) __bf16 bf16x8;
typedef __attribute__((ext_vector_type(4))) float f32x4;
typedef __attribute__((ext_vector_type(8))) u16 ushort8;

// Workspace layout (bytes), total ~71.3 MB
#define OFF_XT  ((size_t)0)          // xT  bf16 [16][4096][128] = 16,777,216
#define OFF_A1  ((size_t)16777216)   // A1  bf16 [16][256][1152] =  9,437,184
#define OFF_A2  ((size_t)26214400)   // A2  bf16 [16][256][2304] = 18,874,368
#define OFF_ASC ((size_t)45088768)   // Asc bf16 [16][256][128]  =  1,048,576
#define OFF_O12 ((size_t)46137344)   // out1/out2 fp32 [16][1024][256] = 16,777,216
#define OFF_YT  ((size_t)62914560)   // yT  bf16 [16][1024][256] =  8,388,608
#define OFF_ST1 ((size_t)71303168)   // 1 KB
#define OFF_ST2 ((size_t)71304192)   // 1 KB
#define OFF_ZP  ((size_t)71305216)   // 512 B zero page

__device__ __forceinline__ u16 f2bf(float f) {
    union { float f; unsigned u; } x; x.f = f;
    unsigned r = x.u + 0x7fffu + ((x.u >> 16) & 1u);   // RNE
    return (u16)(r >> 16);
}

#define GLD16(gp, lp) __builtin_amdgcn_global_load_lds(                    \
        (const __attribute__((address_space(1))) void*)(gp),               \
        (__attribute__((address_space(3))) void*)(lp), 16, 0, 0)

// ---------------------------------------------------------------------------
// x NCHW fp32 -> xT [b][n=4096][ic=128] bf16. Register transpose:
// thread owns one n, 32 ic; scalar loads lane-coalesced, 4x ushort8 stores.
// ---------------------------------------------------------------------------
__global__ void transpose_x_kern(const float* __restrict__ x, u16* __restrict__ xT) {
    const int b = blockIdx.z, ic0 = blockIdx.y * 32;
    const int n = blockIdx.x * 256 + threadIdx.x;
    const float* xp = x + ((size_t)b * 128 + ic0) * 4096 + n;
    u16* op = xT + ((size_t)b * 4096 + n) * 128 + ic0;
    float v[32];
    #pragma unroll
    for (int i = 0; i < 32; ++i) v[i] = xp[(size_t)i * 4096];
    #pragma unroll
    for (int c = 0; c < 4; ++c) {
        ushort8 o;
        #pragma unroll
        for (int j = 0; j < 8; ++j) o[j] = f2bf(v[c * 8 + j]);
        *(ushort8*)(op + c * 8) = o;
    }
}

// ---------------------------------------------------------------------------
// Weight gen as MFMA GEMM: C[16 batches][16 rows] = Z[16,64] x HW[16rows,64]^T
// per wave-tile (2 x mfma_f32_16x16x32_bf16). b-frag read = contiguous 4KB
// block fully consumed by the wave; a-frag (z) is 4KB, L1-resident.
// Output scatter: n -> (oc, kidx=d*ICk+ic), bf16 scalar stores.
// ---------------------------------------------------------------------------
template<int ICk, int KD>
__device__ __forceinline__ void gen_w_tile(const float* __restrict__ hw,
                                           const float* __restrict__ hb,
                                           const float* __restrict__ bw,
                                           const float* __restrict__ z,
                                           u16* __restrict__ A, int wtile) {
    const int lane = threadIdx.x & 63;
    const int l16 = lane & 15, q = lane >> 4;
    const int q8 = q * 8, q4 = q * 4;
    const int n = wtile * 16 + l16;

    union { ushort8 u; bf16x8 h; } za0, za1, wb0, wb1;

    // a-frag: z[batch=l16][k=q8+j]  (first MFMA k<32, second k>=32)
    const float* zp = z + l16 * ZD + q8;
    #pragma unroll
    for (int j = 0; j < 8; ++j) { za0.u[j] = f2bf(zp[j]); za1.u[j] = f2bf(zp[32 + j]); }

    // b-frag: hw[row n][k=q8+j]
    const float* hp = hw + (size_t)n * ZD + q8;
    float4 f0 = *(const float4*)hp,        f1 = *(const float4*)(hp + 4);
    float4 f2 = *(const float4*)(hp + 32), f3 = *(const float4*)(hp + 36);
    wb0.u[0]=f2bf(f0.x); wb0.u[1]=f2bf(f0.y); wb0.u[2]=f2bf(f0.z); wb0.u[3]=f2bf(f0.w);
    wb0.u[4]=f2bf(f1.x); wb0.u[5]=f2bf(f1.y); wb0.u[6]=f2bf(f1.z); wb0.u[7]=f2bf(f1.w);
    wb1.u[0]=f2bf(f2.x); wb1.u[1]=f2bf(f2.y); wb1.u[2]=f2bf(f2.z); wb1.u[3]=f2bf(f2.w);
    wb1.u[4]=f2bf(f3.x); wb1.u[5]=f2bf(f3.y); wb1.u[6]=f2bf(f3.z); wb1.u[7]=f2bf(f3.w);

    f32x4 acc = {0.f, 0.f, 0.f, 0.f};
    acc = __builtin_amdgcn_mfma_f32_16x16x32_bf16(za0.h, wb0.h, acc, 0, 0, 0);
    acc = __builtin_amdgcn_mfma_f32_16x16x32_bf16(za1.h, wb1.h, acc, 0, 0, 0);

    const float base = bw[n] + hb[n];

    // n -> (oc, ic, d); kidx = d*ICk + ic
    const int oc = n / (ICk * KD);
    const int r2 = n - oc * (ICk * KD);
    const int ic = r2 / KD;
    const int dd = r2 - ic * KD;
    const size_t kidx = (size_t)dd * ICk + ic;
    const int K = ICk * KD;

    // D layout: col(n)=lane&15, row(batch)=q*4+r
    #pragma unroll
    for (int r = 0; r < 4; ++r) {
        const int bb = q4 + r;
        A[((size_t)bb * OC + oc) * K + kidx] = f2bf(acc[r] + base);
    }
}

// Horizontally-fused: w2 (9216 blocks) | w1 (4608) | wsc (512). 4 waves/block,
// one 16-row tile per wave.
__global__ __launch_bounds__(256)
void gen_all_kern(const float* __restrict__ hw1, const float* __restrict__ hb1,
                  const float* __restrict__ bw1,
                  const float* __restrict__ hw2, const float* __restrict__ hb2,
                  const float* __restrict__ bw2,
                  const float* __restrict__ hwsc, const float* __restrict__ hbsc,
                  const float* __restrict__ bwsc,
                  const float* __restrict__ z,
                  u16* __restrict__ A1, u16* __restrict__ A2, u16* __restrict__ Asc) {
    const int wid = threadIdx.x >> 6;
    const int bx = blockIdx.x;
    if (bx < 9216) {
        gen_w_tile<256, 9>(hw2, hb2, bw2, z, A2, bx * 4 + wid);
    } else if (bx < 13824) {
        gen_w_tile<128, 9>(hw1, hb1, bw1, z, A1, (bx - 9216) * 4 + wid);
    } else {
        gen_w_tile<128, 1>(hwsc, hbsc, bwsc, z, Asc, (bx - 13824) * 4 + wid);
    }
}

// ---------------------------------------------------------------------------
// GroupNorm stats on NHWC out [b][1024][256]: block per (b,g); cols g*32..+32.
// ---------------------------------------------------------------------------
__global__ void gn_stats_kern(const float* __restrict__ o1, float* __restrict__ stats) {
    const int b = blockIdx.x >> 3, g = blockIdx.x & 7;
    const int t = threadIdx.x;
    float s = 0.f, s2 = 0.f;
    for (int it = 0; it < 32; ++it) {
        const int n = it * 32 + (t >> 3);
        float4 v = *(const float4*)&o1[((size_t)b * 1024 + n) * 256 + g * 32 + (t & 7) * 4];
        s  += v.x + v.y + v.z + v.w;
        s2 += v.x*v.x + v.y*v.y + v.z*v.z + v.w*v.w;
    }
    __shared__ float red[8];
    #pragma unroll
    for (int off = 32; off > 0; off >>= 1) {
        s  += __shfl_down(s,  off);
        s2 += __shfl_down(s2, off);
    }
    const int wid = t >> 6, lane = t & 63;
    if (lane == 0) { red[wid] = s; red[4 + wid] = s2; }
    __syncthreads();
    if (t == 0) {
        s  = red[0] + red[1] + red[2] + red[3];
        s2 = red[4] + red[5] + red[6] + red[7];
        float mean = s * (1.0f / 32768.0f);
        float var  = s2 * (1.0f / 32768.0f) - mean * mean;
        stats[blockIdx.x * 2 + 0] = mean;
        stats[blockIdx.x * 2 + 1] = rsqrtf(var + EPS);
    }
}

// ---------------------------------------------------------------------------
// GN1 apply + ReLU + bf16: out1 [b][n][256] fp32 -> yT [b][n][256] bf16.
// ---------------------------------------------------------------------------
__global__ void gn_apply_kern(const float* __restrict__ o1, const float* __restrict__ stats,
                              const float* __restrict__ gamma, const float* __restrict__ beta,
                              u16* __restrict__ yT) {
    const int gtid = blockIdx.x * 256 + threadIdx.x;
    const int c8 = gtid & 31;
    const int n  = (gtid >> 5) & 1023;
    const int b  = gtid >> 15;
    const int g  = c8 >> 2;
    const float mean = stats[(b * NG_ + g) * 2 + 0];
    const float rstd = stats[(b * NG_ + g) * 2 + 1];
    const float* src = o1 + ((size_t)b * 1024 + n) * 256 + c8 * 8;
    float4 v0 = *(const float4*)src, v1 = *(const float4*)(src + 4);
    float4 g0 = *(const float4*)(gamma + c8 * 8), g1 = *(const float4*)(gamma + c8 * 8 + 4);
    float4 b0 = *(const float4*)(beta  + c8 * 8), b1 = *(const float4*)(beta  + c8 * 8 + 4);
    ushort8 o;
    o[0] = f2bf(fmaxf((v0.x - mean) * rstd * g0.x + b0.x, 0.f));
    o[1] = f2bf(fmaxf((v0.y - mean) * rstd * g0.y + b0.y, 0.f));
    o[2] = f2bf(fmaxf((v0.z - mean) * rstd * g0.z + b0.z, 0.f));
    o[3] = f2bf(fmaxf((v0.w - mean) * rstd * g0.w + b0.w, 0.f));
    o[4] = f2bf(fmaxf((v1.x - mean) * rstd * g1.x + b1.x, 0.f));
    o[5] = f2bf(fmaxf((v1.y - mean) * rstd * g1.y + b1.y, 0.f));
    o[6] = f2bf(fmaxf((v1.z - mean) * rstd * g1.z + b1.z, 0.f));
    o[7] = f2bf(fmaxf((v1.w - mean) * rstd * g1.w + b1.w, 0.f));
    *(ushort8*)(yT + ((size_t)b * 1024 + n) * 256 + c8 * 8) = o;
}

// ---------------------------------------------------------------------------
// Implicit-im2col MFMA conv GEMM.
// D[b][n=spatial 1024][oc=256] (+)= sum_k F_row(m(n,d))[ic] * Wm[b][oc][d*IC+ic]
// F: features [b][IH*IH][IC] bf16 (NHWC). Border rows -> 512B zero page.
// a-frag = spatial rows, b-frag = weight rows => D rows = spatial.
// S-way split over whole taps (KD/S per split). EPI=0: atomicAdd to zeroed C.
// EPI=1: fused GN2-apply(D2) + add + ReLU -> NCHW out (float4 along n).
// ---------------------------------------------------------------------------
template<int IC, int IH, int STRIDE, int KD, int S, int EPI>
__global__ __launch_bounds__(256, 2)
void conv_gemm(const u16* __restrict__ F, const u16* __restrict__ Wm,
               float* __restrict__ C, const u16* __restrict__ zp,
               const float* __restrict__ D2, const float* __restrict__ stats,
               const float* __restrict__ gamma, const float* __restrict__ beta) {
    constexpr int K   = IC * KD;
    constexpr int PAD = (KD == 9) ? 1 : 0;
    constexpr int DPS = KD / S;
    __shared__ __align__(16) u16 As[128 * 32];
    __shared__ __align__(16) u16 Bs[128 * 32];

    const int b  = blockIdx.z / S;
    const int ks = blockIdx.z % S;
    const int m0 = blockIdx.y * 128;     // spatial
    const int n0 = blockIdx.x * 128;     // oc
    const int tid = threadIdx.x, lane = tid & 63, wid = tid >> 6;
    const int wm = (wid >> 1) * 64, wn = (wid & 1) * 64;
    const int lr  = lane >> 2;
    const int lc  = (lane & 3) * 8;      // u16 offset within 64B row segment
    const int l16 = lane & 15, q8 = (lane >> 4) * 8;

    // spatial coords of this lane's two A-staging rows
    const int ra0 = m0 + wid * 16 + lr, ra1 = ra0 + 64;
    const int y0 = ra0 >> 5, x0 = ra0 & 31;
    const int y1 = ra1 >> 5, x1 = ra1 & 31;
    const size_t fb = (size_t)b * IH * IH * IC;

    const u16* q0 = Wm + ((size_t)b * OC + n0 + wid * 16 + lr) * K + lc;
    const u16* q1 = q0 + (size_t)64 * K;

    const f32x4 fzero = {0.f, 0.f, 0.f, 0.f};
    f32x4 acc[4][4];
    #pragma unroll
    for (int i = 0; i < 4; ++i)
        #pragma unroll
        for (int j = 0; j < 4; ++j) acc[i][j] = fzero;

    for (int di = 0; di < DPS; ++di) {
        const int d  = ks * DPS + di;
        const int dy = (KD == 9) ? d / 3 : 0;
        const int dx = (KD == 9) ? d % 3 : 0;
        const int iy0 = STRIDE * y0 + dy - PAD, ix0 = STRIDE * x0 + dx - PAD;
        const int iy1 = STRIDE * y1 + dy - PAD, ix1 = STRIDE * x1 + dx - PAD;
        const bool v0 = ((unsigned)iy0 < (unsigned)IH) && ((unsigned)ix0 < (unsigned)IH);
        const bool v1 = ((unsigned)iy1 < (unsigned)IH) && ((unsigned)ix1 < (unsigned)IH);
        const u16* P0 = v0 ? F + fb + ((size_t)iy0 * IH + ix0) * IC + lc : zp + lc;
        const u16* P1 = v1 ? F + fb + ((size_t)iy1 * IH + ix1) * IC + lc : zp + lc;
        const int kd = d * IC;
        for (int ic0 = 0; ic0 < IC; ic0 += 32) {
            __syncthreads();
            GLD16(P0 + ic0,      &As[(wid * 16) * 32]);
            GLD16(P1 + ic0,      &As[(64 + wid * 16) * 32]);
            GLD16(q0 + kd + ic0, &Bs[(wid * 16) * 32]);
            GLD16(q1 + kd + ic0, &Bs[(64 + wid * 16) * 32]);
            __syncthreads();

            bf16x8 af[4], bfr[4];
            #pragma unroll
            for (int i = 0; i < 4; ++i)
                af[i] = *(const bf16x8*)&As[(wm + i * 16 + l16) * 32 + q8];
            #pragma unroll
            for (int j = 0; j < 4; ++j)
                bfr[j] = *(const bf16x8*)&Bs[(wn + j * 16 + l16) * 32 + q8];
            #pragma unroll
            for (int i = 0; i < 4; ++i)
                #pragma unroll
                for (int j = 0; j < 4; ++j)
                    acc[i][j] = __builtin_amdgcn_mfma_f32_16x16x32_bf16(af[i], bfr[j], acc[i][j], 0, 0, 0);
        }
    }

    const int q4 = (lane >> 4) * 4;
    if (EPI == 0) {
        #pragma unroll
        for (int i = 0; i < 4; ++i)
            #pragma unroll
            for (int j = 0; j < 4; ++j)
                #pragma unroll
                for (int r = 0; r < 4; ++r) {
                    const int ml = m0 + wm + i * 16 + q4 + r;
                    const int nl = n0 + wn + j * 16 + l16;
                    atomicAdd(&C[((size_t)b * 1024 + ml) * 256 + nl], acc[i][j][r]);
                }
    } else {
        #pragma unroll
        for (int j = 0; j < 4; ++j) {
            const int oc = n0 + wn + j * 16 + l16;
            const int gg = oc >> 5;
            const float mean = stats[(b * NG_ + gg) * 2 + 0];
            const float rstd = stats[(b * NG_ + gg) * 2 + 1];
            const float ga = gamma[oc] * rstd;
            const float bb = beta[oc] - mean * ga;
            #pragma unroll
            for (int i = 0; i < 4; ++i) {
                const int nb = m0 + wm + i * 16 + q4;
                float4 o;
                #pragma unroll
                for (int r = 0; r < 4; ++r) {
                    float v = D2[((size_t)b * 1024 + nb + r) * 256 + oc] * ga + bb + acc[i][j][r];
                    ((float*)&o)[r] = fmaxf(v, 0.f);
                }
                *(float4*)&C[((size_t)b * OC + oc) * 1024 + nb] = o;
            }
        }
    }
}

// ---------------------------------------------------------------------------
extern "C" void kernel_launch(void* const* d_in, const int* in_sizes, int n_in,
                              void* d_out, int out_size, void* d_ws, size_t ws_size,
                              hipStream_t stream) {
    const float* x        = (const float*)d_in[0];
    const float* z        = (const float*)d_in[1];
    const float* base_w1  = (const float*)d_in[2];
    const float* head_w1  = (const float*)d_in[3];
    const float* head_b1  = (const float*)d_in[4];
    const float* gn_w1    = (const float*)d_in[5];
    const float* gn_b1    = (const float*)d_in[6];
    const float* base_w2  = (const float*)d_in[7];
    const float* head_w2  = (const float*)d_in[8];
    const float* head_b2  = (const float*)d_in[9];
    const float* gn_w2    = (const float*)d_in[10];
    const float* gn_b2    = (const float*)d_in[11];
    const float* base_wsc = (const float*)d_in[12];
    const float* head_wsc = (const float*)d_in[13];
    const float* head_bsc = (const float*)d_in[14];

    char* ws = (char*)d_ws;
    u16*   xT  = (u16*)(ws + OFF_XT);
    u16*   A1  = (u16*)(ws + OFF_A1);
    u16*   A2  = (u16*)(ws + OFF_A2);
    u16*   Asc = (u16*)(ws + OFF_ASC);
    float* o12 = (float*)(ws + OFF_O12);
    u16*   yT  = (u16*)(ws + OFF_YT);
    float* st1 = (float*)(ws + OFF_ST1);
    float* st2 = (float*)(ws + OFF_ST2);
    u16*   zp  = (u16*)(ws + OFF_ZP);
    float* out = (float*)d_out;

    hipMemsetAsync(zp, 0, 512, stream);
    hipMemsetAsync(o12, 0, (size_t)16777216, stream);

    // x -> NHWC bf16
    transpose_x_kern<<<dim3(16, 4, 16), 256, 0, stream>>>(x, xT);

    // hyper-weight generation: fused MFMA GEMM for all three heads
    gen_all_kern<<<14336, 256, 0, stream>>>(head_w1, head_b1, base_w1,
                                            head_w2, head_b2, base_w2,
                                            head_wsc, head_bsc, base_wsc,
                                            z, A1, A2, Asc);

    // conv1 (3x3 s2) implicit GEMM -> out1 [b][n][oc]
    conv_gemm<128, 64, 2, 9, 3, 0><<<dim3(2, 8, 48), 256, 0, stream>>>(
        xT, A1, o12, zp, nullptr, nullptr, nullptr, nullptr);
    gn_stats_kern<<<B_ * NG_, 256, 0, stream>>>(o12, st1);
    gn_apply_kern<<<2048, 256, 0, stream>>>(o12, st1, gn_w1, gn_b1, yT);

    // conv2 (3x3 s1) implicit GEMM -> out2 [b][n][oc]
    hipMemsetAsync(o12, 0, (size_t)16777216, stream);
    conv_gemm<256, 32, 1, 9, 3, 0><<<dim3(2, 8, 48), 256, 0, stream>>>(
        yT, A2, o12, zp, nullptr, nullptr, nullptr, nullptr);
    gn_stats_kern<<<B_ * NG_, 256, 0, stream>>>(o12, st2);

    // shortcut (1x1 s2) GEMM + fused GN2-apply + add + ReLU -> NCHW out
    conv_gemm<128, 64, 2, 1, 1, 1><<<dim3(2, 8, 16), 256, 0, stream>>>(
        xT, Asc, out, zp, o12, st2, gn_w2, gn_b2);
}